// Round 4
// baseline (785.140 us; speedup 1.0000x reference)
//
#include <hip/hip_runtime.h>

#define B_ 8
#define C_ 32
#define H_ 512
#define W_ 512
#define HW_ (H_ * W_)
#define BN_EPS 1e-5f

typedef float f4v __attribute__((ext_vector_type(4)));

// ws layout: float sums[8] = {sum[o=0..3], sumsq[o=0..3]}

__device__ __forceinline__ void loadch(
    const float* __restrict__ xc, const int off[4],
    const int loff[4], const int roff[4],
    bool jm, bool jp, bool tv, bool bv,
    f4v vr[4], float lf[4], float rt[4])
{
#pragma unroll
    for (int k = 0; k < 4; ++k) {
        vr[k] = *(const f4v*)(xc + off[k]);   // 16B-aligned dwordx4
        lf[k] = xc[loff[k]];                  // L1-hit halo (index pre-clamped)
        rt[k] = xc[roff[k]];
    }
#pragma unroll
    for (int k = 0; k < 4; ++k) {
        if (!jm) lf[k] = 0.f;
        if (!jp) rt[k] = 0.f;
    }
    if (!tv) { vr[0] = f4v{0.f,0.f,0.f,0.f}; lf[0] = 0.f; rt[0] = 0.f; }
    if (!bv) { vr[3] = f4v{0.f,0.f,0.f,0.f}; lf[3] = 0.f; rt[3] = 0.f; }
}

__device__ __forceinline__ void fmach(
    const f4v (*__restrict__ wl4)[C_], int c,
    const f4v vr[4], const float lf[4], const float rt[4],
    f4v acc[2][4])
{
    const f4v wne = wl4[0][c];
    const f4v wnw = wl4[1][c];
    const f4v wse = wl4[2][c];
    const f4v wsw = wl4[3][c];
    const f4v wct = wl4[4][c];
#pragma unroll
    for (int p = 0; p < 2; ++p)
#pragma unroll
        for (int q = 0; q < 4; ++q) {
            const float ne = (q < 3) ? vr[p][q + 1]     : rt[p];
            const float nw = (q > 0) ? vr[p][q - 1]     : lf[p];
            const float se = (q < 3) ? vr[p + 2][q + 1] : rt[p + 2];
            const float sw = (q > 0) ? vr[p + 2][q - 1] : lf[p + 2];
            const float ct = vr[p + 1][q];
            acc[p][q] += wne * ne + wnw * nw + wse * se + wsw * sw + wct * ct;
        }
}

__global__ __launch_bounds__(256, 4) void fourdir_compute(
    const float* __restrict__ x,
    const float* __restrict__ w,
    float* __restrict__ y,
    float* __restrict__ sums)
{
    // Weight LDS: wl4[d][c] = f4v over o (d: 0=ne,1=nw,2=se,3=sw,4=center)
    __shared__ f4v wl4[5][C_];
    const int t = threadIdx.x;
    {
        float* wl = (float*)wl4;
        for (int idx = t; idx < 512; idx += 256) {
            int o  = idx & 3;
            int dc = idx >> 2;
            wl[idx] = w[o * 128 + dc];
        }
    }
    __syncthreads();
    if (t < 128) {
        float* wl = (float*)wl4;
        wl[512 + t] = -(wl[t] + wl[128 + t] + wl[256 + t] + wl[384 + t]);
    }
    __syncthreads();

    // Thread tile: 2 rows x 4 cols. Block tile: 32 rows x 64 cols.
    const int cg = t & 15;            // 16 col groups * 4 cols
    const int rp = t >> 4;            // 16 row pairs * 2 rows
    const int j0 = (blockIdx.x << 6) + (cg << 2);
    const int i0 = (blockIdx.y << 5) + (rp << 1);
    const int b  = blockIdx.z;
    const float* xb = x + (size_t)b * C_ * HW_;

    const bool jm = (j0 > 0);
    const bool jp = (j0 + 4 < W_);
    const bool tv = (i0 > 0);
    const bool bv = (i0 + 2 < H_);

    int off[4], loff[4], roff[4];
    {
        const int rows[4] = { tv ? i0 - 1 : 0, i0, i0 + 1, bv ? i0 + 2 : H_ - 1 };
#pragma unroll
        for (int k = 0; k < 4; ++k) {
            off[k]  = rows[k] * W_ + j0;
            loff[k] = off[k] - (jm ? 1 : 0);   // in-bounds even at j0==0
            roff[k] = off[k] + (jp ? 4 : 3);   // in-bounds even at j0==508
        }
    }

    f4v acc[2][4];
#pragma unroll
    for (int p = 0; p < 2; ++p)
#pragma unroll
        for (int q = 0; q < 4; ++q) acc[p][q] = f4v{0.f, 0.f, 0.f, 0.f};

    // Register double-buffer over channels: load c+1 while FMA'ing c.
    f4v vrA[4], vrB[4];
    float lfA[4], rtA[4], lfB[4], rtB[4];

    loadch(xb, off, loff, roff, jm, jp, tv, bv, vrA, lfA, rtA);
#pragma unroll 1
    for (int c = 0; c < C_ - 2; c += 2) {
        loadch(xb + (size_t)(c + 1) * HW_, off, loff, roff, jm, jp, tv, bv, vrB, lfB, rtB);
        fmach(wl4, c, vrA, lfA, rtA, acc);
        loadch(xb + (size_t)(c + 2) * HW_, off, loff, roff, jm, jp, tv, bv, vrA, lfA, rtA);
        fmach(wl4, c + 1, vrB, lfB, rtB, acc);
    }
    loadch(xb + (size_t)(C_ - 1) * HW_, off, loff, roff, jm, jp, tv, bv, vrB, lfB, rtB);
    fmach(wl4, C_ - 2, vrA, lfA, rtA, acc);
    fmach(wl4, C_ - 1, vrB, lfB, rtB, acc);

    // Write y = [B][4][H][W], aligned float4 per (row, o-plane)
#pragma unroll
    for (int p = 0; p < 2; ++p) {
        const size_t base = (size_t)(i0 + p) * W_ + j0;
#pragma unroll
        for (int o = 0; o < 4; ++o) {
            f4v st = { acc[p][0][o], acc[p][1][o], acc[p][2][o], acc[p][3][o] };
            *(f4v*)(y + ((size_t)(b * 4 + o)) * HW_ + base) = st;
        }
    }

    // Block reduction of sum / sumsq per output channel
    f4v s0 = f4v{0.f,0.f,0.f,0.f}, s1 = f4v{0.f,0.f,0.f,0.f};
#pragma unroll
    for (int p = 0; p < 2; ++p)
#pragma unroll
        for (int q = 0; q < 4; ++q) {
            s0 += acc[p][q];
            s1 += acc[p][q] * acc[p][q];
        }

    float vals[8] = { s0[0], s0[1], s0[2], s0[3], s1[0], s1[1], s1[2], s1[3] };
#pragma unroll
    for (int k = 0; k < 8; ++k) {
        float v = vals[k];
#pragma unroll
        for (int o = 32; o >= 1; o >>= 1) v += __shfl_xor(v, o, 64);
        vals[k] = v;
    }

    __shared__ float red[4][8];
    const int wv   = t >> 6;
    const int lane = t & 63;
    if (lane == 0) {
#pragma unroll
        for (int k = 0; k < 8; ++k) red[wv][k] = vals[k];
    }
    __syncthreads();
    if (t < 8) {
        const float s = red[0][t] + red[1][t] + red[2][t] + red[3][t];
        atomicAdd(&sums[t], s);
    }
}

__global__ __launch_bounds__(256) void bn_norm(
    float* __restrict__ y,
    const float* __restrict__ sums,
    const float* __restrict__ gamma,
    const float* __restrict__ beta)
{
    const int gid = blockIdx.x * 256 + threadIdx.x;       // float4 index
    const size_t base = (size_t)gid * 4;
    const int o = (int)((base / HW_) & 3);                // plane = b*4+o

    const float n = (float)((size_t)B_ * HW_);
    const float mean  = sums[o] / n;
    const float var   = sums[4 + o] / n - mean * mean;
    const float scale = rsqrtf(var + BN_EPS) * gamma[o];
    const float shift = beta[o] - mean * scale;

    float4 v = *(const float4*)(y + base);
    v.x = v.x * scale + shift;
    v.y = v.y * scale + shift;
    v.z = v.z * scale + shift;
    v.w = v.w * scale + shift;
    *(float4*)(y + base) = v;
}

extern "C" void kernel_launch(void* const* d_in, const int* in_sizes, int n_in,
                              void* d_out, int out_size, void* d_ws, size_t ws_size,
                              hipStream_t stream) {
    const float* x     = (const float*)d_in[0];
    const float* w     = (const float*)d_in[1];
    const float* gamma = (const float*)d_in[2];
    const float* beta  = (const float*)d_in[3];
    float* out  = (float*)d_out;
    float* sums = (float*)d_ws;

    // ws is poisoned 0xAA before every launch — zero the accumulators
    hipMemsetAsync(sums, 0, 8 * sizeof(float), stream);

    dim3 gridA(W_ / 64, H_ / 32, B_);   // 8 x 16 x 8 = 1024 blocks (4/CU)
    fourdir_compute<<<gridA, 256, 0, stream>>>(x, w, out, sums);

    const int nf4 = (B_ * 4 * HW_) / 4;   // 2,097,152 float4s
    bn_norm<<<nf4 / 256, 256, 0, stream>>>(out, sums, gamma, beta);
}